// Round 2
// baseline (548.125 us; speedup 1.0000x reference)
//
#include <hip/hip_runtime.h>
#include <hip/hip_bf16.h>

constexpr int cB = 32;
constexpr int cS = 1024;
constexpr int cD = 1280;

#define LN_EPS 1e-5f
#define MASK_FILL -1e9f
#define SCALE 0.02795084971874737f   // 1280^-0.5

// ---------------- q0 = emb[:,0,:] @ Wq^T + bq  (wave per output) -------------
__global__ __launch_bounds__(256) void k_q0(const float* __restrict__ emb,
                                            const float* __restrict__ Wq,
                                            const float* __restrict__ bq,
                                            float* __restrict__ q0) {
    int w = (blockIdx.x * 256 + threadIdx.x) >> 6;   // 0..B*D-1
    int lane = threadIdx.x & 63;
    int b = w / cD, e = w - b * cD;
    const float* a  = emb + (size_t)b * cS * cD;     // row s=0
    const float* wr = Wq + (size_t)e * cD;
    float acc = 0.f;
#pragma unroll
    for (int it = 0; it < cD / 256; ++it) {          // 5 iters, float4/lane
        int d = it * 256 + lane * 4;
        float4 av = *reinterpret_cast<const float4*>(a + d);
        float4 wv = *reinterpret_cast<const float4*>(wr + d);
        acc += av.x * wv.x + av.y * wv.y + av.z * wv.z + av.w * wv.w;
    }
#pragma unroll
    for (int off = 32; off > 0; off >>= 1) acc += __shfl_down(acc, off, 64);
    if (lane == 0) q0[w] = acc + bq[e];
}

// ---------------- qk = q0 @ Wk ; qb = q0 . bk --------------------------------
__global__ __launch_bounds__(256) void k_qk(const float* __restrict__ q0,
                                            const float* __restrict__ Wk,
                                            const float* __restrict__ bk,
                                            float* __restrict__ qk,
                                            float* __restrict__ qb) {
    __shared__ float q0s[cD];
    __shared__ float red[8];
    int b = blockIdx.x / 5, chunk = blockIdx.x % 5;
#pragma unroll
    for (int j = 0; j < 5; ++j)
        q0s[threadIdx.x + 256 * j] = q0[b * cD + threadIdx.x + 256 * j];
    __syncthreads();
    int d = chunk * 256 + threadIdx.x;
    float acc = 0.f;
#pragma unroll 4
    for (int e = 0; e < cD; ++e)
        acc += q0s[e] * Wk[(size_t)e * cD + d];
    qk[b * cD + d] = acc;

    if (chunk == 0) {                                // block-uniform branch
        float pb = 0.f;
        for (int e = threadIdx.x; e < cD; e += 256) pb += q0s[e] * bk[e];
#pragma unroll
        for (int off = 32; off > 0; off >>= 1) pb += __shfl_down(pb, off, 64);
        int wid = threadIdx.x >> 6;
        if ((threadIdx.x & 63) == 0) red[wid] = pb;
        __syncthreads();
        if (threadIdx.x == 0) qb[b] = red[0] + red[1] + red[2] + red[3];
    }
}

// ---------------- scores[b,s] = scale*(emb[b,s].qk[b] + qb[b]) (masked) ------
__global__ __launch_bounds__(256) void k_scores(const float* __restrict__ emb,
                                                const float* __restrict__ qk,
                                                const float* __restrict__ qb,
                                                const int* __restrict__ mask,
                                                float* __restrict__ scores) {
    int w = (blockIdx.x * 256 + threadIdx.x) >> 6;   // 0..B*S-1
    int lane = threadIdx.x & 63;
    int b = w >> 10, s = w & 1023;
    const float* a = emb + (size_t)(b * cS + s) * cD;
    const float* q = qk + b * cD;
    float acc = 0.f;
#pragma unroll
    for (int it = 0; it < cD / 256; ++it) {
        int d = it * 256 + lane * 4;
        float4 av = *reinterpret_cast<const float4*>(a + d);
        float4 qv = *reinterpret_cast<const float4*>(q + d);
        acc += av.x * qv.x + av.y * qv.y + av.z * qv.z + av.w * qv.w;
    }
#pragma unroll
    for (int off = 32; off > 0; off >>= 1) acc += __shfl_down(acc, off, 64);
    if (lane == 0) {
        float sc = (mask[b * cS + s] == 0) ? MASK_FILL : (acc + qb[b]) * SCALE;
        scores[w] = sc;
    }
}

// ---------------- softmax over S per batch -----------------------------------
__global__ __launch_bounds__(256) void k_softmax(const float* __restrict__ scores,
                                                 float* __restrict__ weights) {
    int b = blockIdx.x;
    __shared__ float red[8];
    float v[4];
    float m = -INFINITY;
#pragma unroll
    for (int j = 0; j < 4; ++j) {
        v[j] = scores[b * cS + threadIdx.x + 256 * j];
        m = fmaxf(m, v[j]);
    }
#pragma unroll
    for (int off = 32; off > 0; off >>= 1) m = fmaxf(m, __shfl_xor(m, off, 64));
    int wid = threadIdx.x >> 6, lane = threadIdx.x & 63;
    if (lane == 0) red[wid] = m;
    __syncthreads();
    m = fmaxf(fmaxf(red[0], red[1]), fmaxf(red[2], red[3]));
    float sum = 0.f;
#pragma unroll
    for (int j = 0; j < 4; ++j) { v[j] = expf(v[j] - m); sum += v[j]; }
#pragma unroll
    for (int off = 32; off > 0; off >>= 1) sum += __shfl_xor(sum, off, 64);
    if (lane == 0) red[4 + wid] = sum;
    __syncthreads();
    sum = red[4] + red[5] + red[6] + red[7];
    float inv = 1.f / sum;
#pragma unroll
    for (int j = 0; j < 4; ++j)
        weights[b * cS + threadIdx.x + 256 * j] = v[j] * inv;
}

// ---------------- e_ctx[b,d] = sum_s w[b,s] * emb[b,s,d] ---------------------
__global__ __launch_bounds__(256) void k_ectx(const float* __restrict__ emb,
                                              const float* __restrict__ weights,
                                              float* __restrict__ ectx) {
    __shared__ float wls[cS];
    int b = blockIdx.x / 5, chunk = blockIdx.x % 5;
#pragma unroll
    for (int j = 0; j < 4; ++j)
        wls[threadIdx.x + 256 * j] = weights[b * cS + threadIdx.x + 256 * j];
    __syncthreads();
    int d = chunk * 256 + threadIdx.x;
    const float* base = emb + (size_t)b * cS * cD + d;
    float acc = 0.f;
#pragma unroll 4
    for (int s = 0; s < cS; ++s)
        acc += wls[s] * base[(size_t)s * cD];
    ectx[b * cD + d] = acc;
}

// ---------------- out[b,e] = A[b,:] . W[e,:] + bias[e]  (wave per output) ----
__global__ __launch_bounds__(256) void k_vecmat(const float* __restrict__ A,
                                                const float* __restrict__ W,
                                                const float* __restrict__ bias,
                                                float* __restrict__ out) {
    int w = (blockIdx.x * 256 + threadIdx.x) >> 6;   // 0..B*D-1
    int lane = threadIdx.x & 63;
    int b = w / cD, e = w - b * cD;
    const float* a = A + b * cD;
    const float* wr = W + (size_t)e * cD;
    float acc = 0.f;
#pragma unroll
    for (int it = 0; it < cD / 256; ++it) {
        int d = it * 256 + lane * 4;
        float4 av = *reinterpret_cast<const float4*>(a + d);
        float4 wv = *reinterpret_cast<const float4*>(wr + d);
        acc += av.x * wv.x + av.y * wv.y + av.z * wv.z + av.w * wv.w;
    }
#pragma unroll
    for (int off = 32; off > 0; off >>= 1) acc += __shfl_down(acc, off, 64);
    if (lane == 0) out[w] = acc + bias[e];
}

// ---------------- LayerNorm + ReLU -------------------------------------------
__global__ __launch_bounds__(256) void k_ln(const float* __restrict__ h,
                                            const float* __restrict__ gamma,
                                            const float* __restrict__ beta,
                                            float* __restrict__ out) {
    int b = blockIdx.x;
    __shared__ float red[8];
    int wid = threadIdx.x >> 6, lane = threadIdx.x & 63;
    float v[5];
    float sum = 0.f;
#pragma unroll
    for (int j = 0; j < 5; ++j) {
        v[j] = h[b * cD + threadIdx.x + 256 * j];
        sum += v[j];
    }
#pragma unroll
    for (int off = 32; off > 0; off >>= 1) sum += __shfl_xor(sum, off, 64);
    if (lane == 0) red[wid] = sum;
    __syncthreads();
    float mu = (red[0] + red[1] + red[2] + red[3]) * (1.f / cD);
    float vs = 0.f;
#pragma unroll
    for (int j = 0; j < 5; ++j) { float t = v[j] - mu; vs += t * t; }
#pragma unroll
    for (int off = 32; off > 0; off >>= 1) vs += __shfl_xor(vs, off, 64);
    if (lane == 0) red[4 + wid] = vs;
    __syncthreads();
    float var = (red[4] + red[5] + red[6] + red[7]) * (1.f / cD);
    float inv = rsqrtf(var + LN_EPS);
#pragma unroll
    for (int j = 0; j < 5; ++j) {
        int idx = threadIdx.x + 256 * j;
        float o = (v[j] - mu) * inv * gamma[idx] + beta[idx];
        out[b * cD + idx] = fmaxf(o, 0.f);
    }
}

extern "C" void kernel_launch(void* const* d_in, const int* in_sizes, int n_in,
                              void* d_out, int out_size, void* d_ws, size_t ws_size,
                              hipStream_t stream) {
    const float* emb   = (const float*)d_in[0];
    const int*   mask  = (const int*)d_in[1];
    const float* Wq    = (const float*)d_in[2];
    const float* bq    = (const float*)d_in[3];
    const float* Wk    = (const float*)d_in[4];
    const float* bk    = (const float*)d_in[5];
    const float* Wv    = (const float*)d_in[6];
    const float* bv    = (const float*)d_in[7];
    const float* Wo    = (const float*)d_in[8];
    const float* bo    = (const float*)d_in[9];
    const float* gamma = (const float*)d_in[10];
    const float* beta  = (const float*)d_in[11];

    float* ws      = (float*)d_ws;
    float* q0      = ws;                  // 40960
    float* qk      = q0 + cB * cD;        // 40960
    float* qb      = qk + cB * cD;        // 32
    float* scores  = qb + cB;             // 32768
    float* weights = scores + cB * cS;    // 32768
    float* ectx    = weights + cB * cS;   // 40960
    float* ctx     = ectx + cB * cD;      // 40960
    float* h       = ctx + cB * cD;       // 40960

    k_q0<<<cB * cD / 4, 256, 0, stream>>>(emb, Wq, bq, q0);
    k_qk<<<cB * 5, 256, 0, stream>>>(q0, Wk, bk, qk, qb);
    k_scores<<<cB * cS / 4, 256, 0, stream>>>(emb, qk, qb, mask, scores);
    k_softmax<<<cB, 256, 0, stream>>>(scores, weights);
    k_ectx<<<cB * 5, 256, 0, stream>>>(emb, weights, ectx);
    k_vecmat<<<cB * cD / 4, 256, 0, stream>>>(ectx, Wv, bv, ctx);
    k_vecmat<<<cB * cD / 4, 256, 0, stream>>>(ctx, Wo, bo, h);
    k_ln<<<cB, 256, 0, stream>>>(h, gamma, beta, (float*)d_out);
}

// Round 3
// 354.848 us; speedup vs baseline: 1.5447x; 1.5447x over previous
//
#include <hip/hip_runtime.h>
#include <hip/hip_bf16.h>

constexpr int cB = 32;
constexpr int cS = 1024;
constexpr int cD = 1280;
constexpr int KC = 32;          // k-chunk for split-K matmuls
constexpr int NKC = cD / KC;    // 40 k-chunks
constexpr int NNC = cD / 256;   // 5 n-chunks

#define LN_EPS 1e-5f
#define MASK_FILL -1e9f
#define SCALE 0.02795084971874737f   // 1280^-0.5

// ============================================================================
// Split-K matmul, phase 1, B accessed as W^T (W row-major [N,K]):
//   part[kc][b][n] = sum_{k in chunk} A[b, k] * W[n, k]
// W tile is staged through LDS (transposed, padded) for coalesced global reads.
// A operands are wave-uniform -> scalar loads feeding v_fmac.
// ============================================================================
__global__ __launch_bounds__(256) void k_mmT_p1(const float* __restrict__ A,
                                                size_t lda,
                                                const float* __restrict__ W,
                                                float* __restrict__ part) {
    __shared__ float s_t[KC * 257];
    int t = threadIdx.x;
    int nc = blockIdx.x % NNC, kc = blockIdx.x / NNC;
    int n0 = nc * 256, k0 = kc * KC;

    // stage W[n0:n0+256, k0:k0+32] into s_t[k][n] (padded stride 257)
#pragma unroll
    for (int p = 0; p < 8; ++p) {
        int r  = (t >> 3) + p * 32;        // n_local
        int ko = (t & 7) * 4;              // k_local
        float4 wv = *reinterpret_cast<const float4*>(W + (size_t)(n0 + r) * cD + k0 + ko);
        s_t[(ko + 0) * 257 + r] = wv.x;
        s_t[(ko + 1) * 257 + r] = wv.y;
        s_t[(ko + 2) * 257 + r] = wv.z;
        s_t[(ko + 3) * 257 + r] = wv.w;
    }
    __syncthreads();

    float w[KC];
#pragma unroll
    for (int kk = 0; kk < KC; ++kk) w[kk] = s_t[kk * 257 + t];

#pragma unroll
    for (int b = 0; b < cB; ++b) {
        const float* Ab = A + (size_t)b * lda + k0;   // wave-uniform -> s_load
        float a0 = 0.f, a1 = 0.f, a2 = 0.f, a3 = 0.f;
#pragma unroll
        for (int kk = 0; kk < KC; kk += 4) {
            a0 += Ab[kk + 0] * w[kk + 0];
            a1 += Ab[kk + 1] * w[kk + 1];
            a2 += Ab[kk + 2] * w[kk + 2];
            a3 += Ab[kk + 3] * w[kk + 3];
        }
        part[(size_t)kc * (cB * cD) + b * cD + n0 + t] = (a0 + a1) + (a2 + a3);
    }
}

// ============================================================================
// Split-K matmul, phase 1, B accessed directly (B row-major [K,N]):
//   part[kc][b][n] = sum_{k in chunk} A[b, k] * B[k, n]
// ============================================================================
__global__ __launch_bounds__(256) void k_mm_p1(const float* __restrict__ A,
                                               size_t lda,
                                               const float* __restrict__ B,
                                               float* __restrict__ part) {
    int t = threadIdx.x;
    int nc = blockIdx.x % NNC, kc = blockIdx.x / NNC;
    int n0 = nc * 256, k0 = kc * KC;

    float w[KC];
#pragma unroll
    for (int kk = 0; kk < KC; ++kk)
        w[kk] = B[(size_t)(k0 + kk) * cD + n0 + t];   // coalesced

#pragma unroll
    for (int b = 0; b < cB; ++b) {
        const float* Ab = A + (size_t)b * lda + k0;   // wave-uniform -> s_load
        float a0 = 0.f, a1 = 0.f, a2 = 0.f, a3 = 0.f;
#pragma unroll
        for (int kk = 0; kk < KC; kk += 4) {
            a0 += Ab[kk + 0] * w[kk + 0];
            a1 += Ab[kk + 1] * w[kk + 1];
            a2 += Ab[kk + 2] * w[kk + 2];
            a3 += Ab[kk + 3] * w[kk + 3];
        }
        part[(size_t)kc * (cB * cD) + b * cD + n0 + t] = (a0 + a1) + (a2 + a3);
    }
}

// ---------------- phase 2: sum partials (+optional bias) ---------------------
__global__ __launch_bounds__(256) void k_mm_red(const float* __restrict__ part,
                                                const float* __restrict__ bias,
                                                float* __restrict__ out) {
    int i = blockIdx.x * 256 + threadIdx.x;           // 0..cB*cD-1
    float s = 0.f;
#pragma unroll
    for (int c = 0; c < NKC; ++c) s += part[(size_t)c * (cB * cD) + i];
    if (bias) s += bias[i % cD];
    out[i] = s;
}

// ---------------- qb[b] = q0[b,:] . bk ---------------------------------------
__global__ __launch_bounds__(256) void k_qb(const float* __restrict__ q0,
                                            const float* __restrict__ bk,
                                            float* __restrict__ qb) {
    int w = threadIdx.x >> 6, lane = threadIdx.x & 63;
    int d0 = lane * 4;
    float4 bkr[5];
#pragma unroll
    for (int it = 0; it < 5; ++it)
        bkr[it] = *reinterpret_cast<const float4*>(bk + it * 256 + d0);
#pragma unroll
    for (int r = 0; r < 8; ++r) {
        int b = w * 8 + r;
        float dot = 0.f;
#pragma unroll
        for (int it = 0; it < 5; ++it) {
            float4 qv = *reinterpret_cast<const float4*>(q0 + b * cD + it * 256 + d0);
            dot += qv.x * bkr[it].x + qv.y * bkr[it].y + qv.z * bkr[it].z + qv.w * bkr[it].w;
        }
#pragma unroll
        for (int off = 32; off; off >>= 1) dot += __shfl_xor(dot, off, 64);
        if (lane == 0) qb[b] = dot;
    }
}

// ============================================================================
// Fused flash-style: scores + online softmax + weighted emb sum, single pass.
// Grid: b*32 + sc ; block 256 = 4 waves ; wave handles 8 consecutive s-rows.
// ============================================================================
__global__ __launch_bounds__(256) void k_attn(const float* __restrict__ emb,
                                              const float* __restrict__ qk,
                                              const float* __restrict__ qb,
                                              const int* __restrict__ mask,
                                              float* __restrict__ pm,
                                              float* __restrict__ pl,
                                              float* __restrict__ pacc) {
    int blk = blockIdx.x;
    int b = blk >> 5, sc = blk & 31;
    int w = threadIdx.x >> 6, lane = threadIdx.x & 63;
    int d0 = lane * 4;

    float4 qkr[5];
#pragma unroll
    for (int it = 0; it < 5; ++it)
        qkr[it] = *reinterpret_cast<const float4*>(qk + b * cD + it * 256 + d0);
    float qbv = qb[b];

    float m = -INFINITY, l = 0.f;
    float4 acc[5];
#pragma unroll
    for (int it = 0; it < 5; ++it) acc[it] = make_float4(0.f, 0.f, 0.f, 0.f);

    int s0 = sc * 32 + w * 8;
    for (int r = 0; r < 8; ++r) {
        int s = s0 + r;
        const float* e = emb + (size_t)(b * cS + s) * cD + d0;
        float4 er[5];
#pragma unroll
        for (int it = 0; it < 5; ++it)
            er[it] = *reinterpret_cast<const float4*>(e + it * 256);
        float dot = 0.f;
#pragma unroll
        for (int it = 0; it < 5; ++it)
            dot += er[it].x * qkr[it].x + er[it].y * qkr[it].y
                 + er[it].z * qkr[it].z + er[it].w * qkr[it].w;
#pragma unroll
        for (int off = 32; off; off >>= 1) dot += __shfl_xor(dot, off, 64);
        float scv = (mask[b * cS + s] == 0) ? MASK_FILL : (dot + qbv) * SCALE;
        if (scv > m) {                       // wave-uniform branch
            float f = __expf(m - scv);
            l *= f;
#pragma unroll
            for (int it = 0; it < 5; ++it) {
                acc[it].x *= f; acc[it].y *= f; acc[it].z *= f; acc[it].w *= f;
            }
            m = scv;
        }
        float p = __expf(scv - m);
        l += p;
#pragma unroll
        for (int it = 0; it < 5; ++it) {
            acc[it].x += p * er[it].x; acc[it].y += p * er[it].y;
            acc[it].z += p * er[it].z; acc[it].w += p * er[it].w;
        }
    }

    // ---- block combine (4 waves) ----
    __shared__ float s_m[4], s_l[4];
    __shared__ float s_acc[cD];
    if (lane == 0) { s_m[w] = m; s_l[w] = l; }
    __syncthreads();
    float M = fmaxf(fmaxf(s_m[0], s_m[1]), fmaxf(s_m[2], s_m[3]));
    float f = __expf(m - M);                 // wave-uniform
    if (w == 0) {
#pragma unroll
        for (int it = 0; it < 5; ++it)
            *reinterpret_cast<float4*>(s_acc + it * 256 + d0) =
                make_float4(acc[it].x * f, acc[it].y * f, acc[it].z * f, acc[it].w * f);
    }
    __syncthreads();
    if (w == 1) {
#pragma unroll
        for (int it = 0; it < 5; ++it) {
            float4* p4 = reinterpret_cast<float4*>(s_acc + it * 256 + d0);
            float4 v = *p4;
            *p4 = make_float4(v.x + acc[it].x * f, v.y + acc[it].y * f,
                              v.z + acc[it].z * f, v.w + acc[it].w * f);
        }
    }
    __syncthreads();
    if (w == 2) {
#pragma unroll
        for (int it = 0; it < 5; ++it) {
            float4* p4 = reinterpret_cast<float4*>(s_acc + it * 256 + d0);
            float4 v = *p4;
            *p4 = make_float4(v.x + acc[it].x * f, v.y + acc[it].y * f,
                              v.z + acc[it].z * f, v.w + acc[it].w * f);
        }
    }
    __syncthreads();
    if (w == 3) {
#pragma unroll
        for (int it = 0; it < 5; ++it) {
            float4* p4 = reinterpret_cast<float4*>(s_acc + it * 256 + d0);
            float4 v = *p4;
            *p4 = make_float4(v.x + acc[it].x * f, v.y + acc[it].y * f,
                              v.z + acc[it].z * f, v.w + acc[it].w * f);
        }
    }
    __syncthreads();

    if (threadIdx.x == 0) {
        float lt = s_l[0] * __expf(s_m[0] - M) + s_l[1] * __expf(s_m[1] - M)
                 + s_l[2] * __expf(s_m[2] - M) + s_l[3] * __expf(s_m[3] - M);
        pm[blk] = M; pl[blk] = lt;
    }
#pragma unroll
    for (int j = 0; j < 5; ++j)
        pacc[(size_t)blk * cD + threadIdx.x + 256 * j] = s_acc[threadIdx.x + 256 * j];
}

// ---------------- combine 32 partials per batch -> ectx ----------------------
__global__ __launch_bounds__(256) void k_attn_red(const float* __restrict__ pm,
                                                  const float* __restrict__ pl,
                                                  const float* __restrict__ pacc,
                                                  float* __restrict__ ectx) {
    int b = blockIdx.x / 5, j = blockIdx.x % 5;
    int d = j * 256 + threadIdx.x;
    float M = -INFINITY;
    for (int i = 0; i < 32; ++i) M = fmaxf(M, pm[b * 32 + i]);
    float L = 0.f, a = 0.f;
    for (int i = 0; i < 32; ++i) {
        float wf = __expf(pm[b * 32 + i] - M);
        L += pl[b * 32 + i] * wf;
        a += wf * pacc[(size_t)(b * 32 + i) * cD + d];
    }
    ectx[b * cD + d] = a / L;
}

// ---------------- LayerNorm + ReLU -------------------------------------------
__global__ __launch_bounds__(256) void k_ln(const float* __restrict__ h,
                                            const float* __restrict__ gamma,
                                            const float* __restrict__ beta,
                                            float* __restrict__ out) {
    int b = blockIdx.x;
    __shared__ float red[8];
    int wid = threadIdx.x >> 6, lane = threadIdx.x & 63;
    float v[5];
    float sum = 0.f;
#pragma unroll
    for (int j = 0; j < 5; ++j) {
        v[j] = h[b * cD + threadIdx.x + 256 * j];
        sum += v[j];
    }
#pragma unroll
    for (int off = 32; off; off >>= 1) sum += __shfl_xor(sum, off, 64);
    if (lane == 0) red[wid] = sum;
    __syncthreads();
    float mu = (red[0] + red[1] + red[2] + red[3]) * (1.f / cD);
    float vs = 0.f;
#pragma unroll
    for (int j = 0; j < 5; ++j) { float t = v[j] - mu; vs += t * t; }
#pragma unroll
    for (int off = 32; off; off >>= 1) vs += __shfl_xor(vs, off, 64);
    if (lane == 0) red[4 + wid] = vs;
    __syncthreads();
    float var = (red[4] + red[5] + red[6] + red[7]) * (1.f / cD);
    float inv = rsqrtf(var + LN_EPS);
#pragma unroll
    for (int j = 0; j < 5; ++j) {
        int idx = threadIdx.x + 256 * j;
        float o = (v[j] - mu) * inv * gamma[idx] + beta[idx];
        out[b * cD + idx] = fmaxf(o, 0.f);
    }
}

extern "C" void kernel_launch(void* const* d_in, const int* in_sizes, int n_in,
                              void* d_out, int out_size, void* d_ws, size_t ws_size,
                              hipStream_t stream) {
    const float* emb   = (const float*)d_in[0];
    const int*   mask  = (const int*)d_in[1];
    const float* Wq    = (const float*)d_in[2];
    const float* bq    = (const float*)d_in[3];
    const float* Wk    = (const float*)d_in[4];
    const float* bk    = (const float*)d_in[5];
    const float* Wv    = (const float*)d_in[6];
    const float* bv    = (const float*)d_in[7];
    const float* Wo    = (const float*)d_in[8];
    const float* bo    = (const float*)d_in[9];
    const float* gamma = (const float*)d_in[10];
    const float* beta  = (const float*)d_in[11];

    float* ws   = (float*)d_ws;
    float* part = ws;                        // 40*32*1280 = 1,638,400
    float* q0   = part + NKC * cB * cD;      // 40960
    float* qk   = q0 + cB * cD;              // 40960
    float* qb   = qk + cB * cD;              // 32
    float* pm   = qb + cB;                   // 1024
    float* pl   = pm + 1024;                 // 1024
    float* pacc = pl + 1024;                 // 1024*1280 = 1,310,720
    float* ectx = pacc + (size_t)1024 * cD;  // 40960
    float* ctx  = ectx + cB * cD;            // 40960
    float* h    = ctx + cB * cD;             // 40960

    const int mmGrid  = NNC * NKC;           // 200
    const int redGrid = cB * cD / 256;       // 160

    // q0 = emb[:,0,:] @ Wq^T + bq
    k_mmT_p1<<<mmGrid, 256, 0, stream>>>(emb, (size_t)cS * cD, Wq, part);
    k_mm_red<<<redGrid, 256, 0, stream>>>(part, bq, q0);
    // qb = q0 . bk
    k_qb<<<1, 256, 0, stream>>>(q0, bk, qb);
    // qk = q0 @ Wk   (no bias; bk folded into qb)
    k_mm_p1<<<mmGrid, 256, 0, stream>>>(q0, (size_t)cD, Wk, part);
    k_mm_red<<<redGrid, 256, 0, stream>>>(part, nullptr, qk);
    // fused scores + softmax + weighted emb sum
    k_attn<<<cB * 32, 256, 0, stream>>>(emb, qk, qb, mask, pm, pl, pacc);
    k_attn_red<<<redGrid, 256, 0, stream>>>(pm, pl, pacc, ectx);
    // ctx = ectx @ Wv^T + bv
    k_mmT_p1<<<mmGrid, 256, 0, stream>>>(ectx, (size_t)cD, Wv, part);
    k_mm_red<<<redGrid, 256, 0, stream>>>(part, bv, ctx);
    // h = ctx @ Wo^T + bo
    k_mmT_p1<<<mmGrid, 256, 0, stream>>>(ctx, (size_t)cD, Wo, part);
    k_mm_red<<<redGrid, 256, 0, stream>>>(part, bo, h);
    // LayerNorm + ReLU
    k_ln<<<cB, 256, 0, stream>>>(h, gamma, beta, (float*)d_out);
}